// Round 6
// baseline (332.222 us; speedup 1.0000x reference)
//
#include <hip/hip_runtime.h>
#include <math.h>

#define T_ 8
#define B_ 4
#define C_ 128
#define HW_ 9216        // 96*96
#define IN_HW_ 147456   // 384*384

typedef float nat_f4 __attribute__((ext_vector_type(4)));  // nontemporal stores

// f64 filter weights (8-tap triangle, edge-renormalized)
__device__ static const double d_wm[8]  = {0.03125, 0.09375, 0.15625, 0.21875,
                                           0.21875, 0.15625, 0.09375, 0.03125};
__device__ static const double d_w0[8]  = {0.0, 0.0, 0.625/3.5, 0.875/3.5,
                                           0.875/3.5, 0.625/3.5, 0.375/3.5, 0.125/3.5};
__device__ static const double d_w95[8] = {0.125/3.5, 0.375/3.5, 0.625/3.5, 0.875/3.5,
                                           0.875/3.5, 0.625/3.5, 0.0, 0.0};

// shuffle+LDS block sum (256 threads). Trailing sync: safe to call repeatedly.
__device__ __forceinline__ float block_sum_256(float v) {
  v += __shfl_xor(v, 1);
  v += __shfl_xor(v, 2);
  v += __shfl_xor(v, 4);
  v += __shfl_xor(v, 8);
  v += __shfl_xor(v, 16);
  v += __shfl_xor(v, 32);
  __shared__ float s[4];
  int lane = threadIdx.x & 63, wv = threadIdx.x >> 6;
  if (lane == 0) s[wv] = v;
  __syncthreads();
  float r = s[0] + s[1] + s[2] + s[3];
  __syncthreads();
  return r;
}

// ---------------------------------------------------------------------------
// k_resize: 384->96 antialias resize + binarize for all 36 mask images.
// (verified in round 5 -- unchanged)
// ---------------------------------------------------------------------------
__global__ __launch_bounds__(384) void k_resize(const float* __restrict__ rvmaps,
                                                const float* __restrict__ tvmap,
                                                float* __restrict__ rv,
                                                float* __restrict__ tv) {
  const int job = blockIdx.y;
  const float* img = (job < 32) ? rvmaps + (size_t)job * IN_HW_
                                : tvmap  + (size_t)(job - 32) * IN_HW_;
  float* dst = (job < 32) ? rv + (size_t)job * HW_
                          : tv + (size_t)(job - 32) * HW_;
  const int x  = threadIdx.x % 96;
  const int yg = threadIdx.x / 96;           // 0..3
  const int y0 = blockIdx.x * 16 + yg * 4;   // 4 output rows per thread

  const double* wys[4];
#pragma unroll
  for (int i = 0; i < 4; ++i) {
    int y = y0 + i;
    wys[i] = (y == 0) ? d_w0 : (y == 95 ? d_w95 : d_wm);
  }

  double acc0 = 0.0, acc1 = 0.0, acc2 = 0.0, acc3 = 0.0;
  const int base = 4 * y0 - 2;                       // ky = jy - base - 4*i
  const int jy_lo = base < 0 ? 0 : base;
  const int jy_hi_raw = 4 * (y0 + 3) + 5;
  const int jy_hi = jy_hi_raw > 383 ? 383 : jy_hi_raw;

  for (int jy = jy_lo; jy <= jy_hi; ++jy) {
    const float* row = img + (size_t)jy * 384;
    double ra;
    if (x == 0) {
      const float4 q0 = *(const float4*)(row);       // jx 0..3
      const float4 q1 = *(const float4*)(row + 4);   // jx 4..7
      ra = d_w0[2] * (double)q0.x + d_w0[3] * (double)q0.y +
           d_w0[4] * (double)q0.z + d_w0[5] * (double)q0.w +
           d_w0[6] * (double)q1.x + d_w0[7] * (double)q1.y;
    } else if (x == 95) {
      const float4 q0 = *(const float4*)(row + 376); // jx 376..379
      const float4 q1 = *(const float4*)(row + 380); // jx 380..383
      ra = d_w95[0] * (double)q0.z + d_w95[1] * (double)q0.w +
           d_w95[2] * (double)q1.x + d_w95[3] * (double)q1.y +
           d_w95[4] * (double)q1.z + d_w95[5] * (double)q1.w;
    } else {
      const int b0 = 4 * x - 4;                      // multiple of 4 -> 16B aligned
      const float4 q0 = *(const float4*)(row + b0);
      const float4 q1 = *(const float4*)(row + b0 + 4);
      const float4 q2 = *(const float4*)(row + b0 + 8);
      ra = d_wm[0] * (double)q0.z + d_wm[1] * (double)q0.w +
           d_wm[2] * (double)q1.x + d_wm[3] * (double)q1.y +
           d_wm[4] * (double)q1.z + d_wm[5] * (double)q1.w +
           d_wm[6] * (double)q2.x + d_wm[7] * (double)q2.y;
    }
    {
      int ky = jy - base;
      if (ky >= 0 && ky < 8) acc0 += wys[0][ky] * ra;
      ky -= 4;
      if (ky >= 0 && ky < 8) acc1 += wys[1][ky] * ra;
      ky -= 4;
      if (ky >= 0 && ky < 8) acc2 += wys[2][ky] * ra;
      ky -= 4;
      if (ky >= 0 && ky < 8) acc3 += wys[3][ky] * ra;
    }
  }
  dst[(size_t)(y0 + 0) * 96 + x] = (acc0 > 0.5) ? 1.0f : 0.0f;
  dst[(size_t)(y0 + 1) * 96 + x] = (acc1 > 0.5) ? 1.0f : 0.0f;
  dst[(size_t)(y0 + 2) * 96 + x] = (acc2 > 0.5) ? 1.0f : 0.0f;
  dst[(size_t)(y0 + 3) * 96 + x] = (acc3 > 0.5) ? 1.0f : 0.0f;
}

// ---------------------------------------------------------------------------
// k_gs: t-major gs partials + t_feat passthrough.
// grid (3, C_, B_) = 1536 blocks x 256. Each thread accumulates 3 float4
// tiles (3072 px per block) into acc[8], then ONE shuffle reduction per
// block (was one per 1024-px block -> 3x less reduction/sync overhead).
// gs_part layout: [(t*B+b)][c][ptile3]  (384 floats per tb).
// ---------------------------------------------------------------------------
__global__ __launch_bounds__(256) void k_gs(const float* __restrict__ values,
                                            const float* __restrict__ rv,
                                            const float* __restrict__ tv,
                                            float* __restrict__ gs_part,
                                            float* __restrict__ out) {
  const int ptile = blockIdx.x;       // 0..2 (3072 px each)
  const int c     = blockIdx.y;       // 0..127
  const int b     = blockIdx.z;       // 0..3
  const int tid   = threadIdx.x;

  float acc[T_];
#pragma unroll
  for (int t = 0; t < T_; ++t) acc[t] = 0.f;

#pragma unroll
  for (int i = 0; i < 3; ++i) {
    const int p0 = ptile * 3072 + i * 1024 + tid * 4;
    const float4 a   = *(const float4*)(values + ((size_t)b * C_ + c) * HW_ + p0);
    const float4 tvv = *(const float4*)(tv + (size_t)b * HW_ + p0);
    // t_feat passthrough (out channels 0..127)
    {
      nat_f4 an = {a.x, a.y, a.z, a.w};
      __builtin_nontemporal_store(an,
          (nat_f4*)(out + (size_t)b * 257 * HW_ + (size_t)c * HW_ + p0));
    }
#pragma unroll
    for (int t = 0; t < T_; ++t) {
      const float4 rv4 = *(const float4*)(rv + ((size_t)(t * B_ + b)) * HW_ + p0);
      const float4 r = *(const float4*)(values + ((size_t)((1 + t) * B_ + b) * C_ + c) * HW_ + p0);
      acc[t] += (rv4.x * tvv.x) * a.x * r.x + (rv4.y * tvv.y) * a.y * r.y +
                (rv4.z * tvv.z) * a.z * r.z + (rv4.w * tvv.w) * a.w * r.w;
    }
  }

  __shared__ float sred[4][T_];
  const int lane = tid & 63, wv = tid >> 6;
#pragma unroll
  for (int t = 0; t < T_; ++t) {
    float v = acc[t];
    v += __shfl_xor(v, 1);
    v += __shfl_xor(v, 2);
    v += __shfl_xor(v, 4);
    v += __shfl_xor(v, 8);
    v += __shfl_xor(v, 16);
    v += __shfl_xor(v, 32);
    if (lane == 0) sred[wv][t] = v;
  }
  __syncthreads();
  if (tid < T_) {
    const int t = tid;
    const float s = sred[0][t] + sred[1][t] + sred[2][t] + sred[3][t];
    gs_part[(size_t)(t * B_ + b) * (C_ * 3) + c * 3 + ptile] = s;
  }
}

// ---------------------------------------------------------------------------
// k_epi: gs finalize (recomputed per block from L2-resident data; exact) +
// per-pixel softmax over t + c_out (8 ch/block) + cmask + out_gs.
// grid: (16 ctiles of 8 ch, 9 ptiles, B_) = 576 blocks x 256, 4 px/thread.
// ---------------------------------------------------------------------------
__global__ __launch_bounds__(256) void k_epi(const float* __restrict__ values,
                                             const float* __restrict__ rv,
                                             const float* __restrict__ tv,
                                             const float* __restrict__ gs_part,
                                             float* __restrict__ out,
                                             float* __restrict__ out_cmask,
                                             float* __restrict__ out_gs) {
  const int ctile = blockIdx.x;       // 0..15
  const int ptile = blockIdx.y;       // 0..8
  const int b     = blockIdx.z;       // 0..3
  const int tid   = threadIdx.x;

  // ---- Phase 1: recompute gs[0..7] for this b (deterministic, L2-hit) ----
  // v_sum[t] = sum_p rv[t,b,p]*tv[b,p]  (exact 0/1 integer sum)
  float vsum[T_];
#pragma unroll
  for (int t = 0; t < T_; ++t) vsum[t] = 0.f;
  {
    const float4* pt = (const float4*)(tv + (size_t)b * HW_);
    for (int i = tid; i < HW_ / 4; i += 256) {    // 9 iters
      const float4 tvv = pt[i];
#pragma unroll
      for (int t = 0; t < T_; ++t) {
        const float4 r = ((const float4*)(rv + ((size_t)(t * B_ + b)) * HW_))[i];
        vsum[t] += r.x * tvv.x + r.y * tvv.y + r.z * tvv.z + r.w * tvv.w;
      }
    }
  }
  __shared__ float gsh[T_];
#pragma unroll
  for (int t = 0; t < T_; ++t) {
    const float vs = block_sum_256(vsum[t]);
    // gs_part sum for (t,b): 384 floats = 96 float4, lanes 0..95
    float s = 0.f;
    if (tid < 96) {
      const float4 v = ((const float4*)(gs_part + (size_t)(t * B_ + b) * (C_ * 3)))[tid];
      s = v.x + v.y + v.z + v.w;
    }
    s = block_sum_256(s);
    if (tid == 0) {
      const bool empty = vs < 1e-4f;
      gsh[t] = (empty ? 0.f : s) / (vs + (empty ? 1.f : 0.f)) / (float)C_;
    }
  }
  __syncthreads();
  if (ctile == 0 && ptile == 0 && tid < T_)
    out_gs[tid * B_ + b] = gsh[tid];

  // ---- Phase 2: softmax + c_out + cmask ----------------------------------
  const int p0 = ptile * 1024 + tid * 4;

  float4 rv4[T_];
#pragma unroll
  for (int t = 0; t < T_; ++t)
    rv4[t] = *(const float4*)(rv + ((size_t)(t * B_ + b)) * HW_ + p0);

  float cm[T_][4];
  float cmask[4];
#pragma unroll
  for (int j = 0; j < 4; ++j) {
    float mv[T_];
    float mx = -1e30f;
#pragma unroll
    for (int t = 0; t < T_; ++t) {
      const float rvv = ((const float*)&rv4[t])[j];
      mv[t] = gsh[t] * rvv;
      mx = fmaxf(mx, mv[t]);
    }
    float e[T_];
    float ms = 0.f;
#pragma unroll
    for (int t = 0; t < T_; ++t) {
      const float rvv = ((const float*)&rv4[t])[j];
      e[t] = __expf(mv[t] - mx) * rvv;
      ms += e[t];
    }
    if (ms < 1e-4f) ms += 1.f;
    const float inv = 1.f / ms;
    float cs = 0.f;
#pragma unroll
    for (int t = 0; t < T_; ++t) {
      cm[t][j] = e[t] * inv;
      cs += cm[t][j] * ((const float*)&rv4[t])[j];
    }
    cmask[j] = 1.f - cs;
  }

  const size_t outb = (size_t)b * 257 * HW_;
#pragma unroll 1
  for (int cc = 0; cc < 8; ++cc) {
    const int c = ctile * 8 + cc;
    float4 acc = {0.f, 0.f, 0.f, 0.f};
#pragma unroll
    for (int t = 0; t < T_; ++t) {
      const float4 r = *(const float4*)(values +
          ((size_t)((1 + t) * B_ + b) * C_ + c) * HW_ + p0);
      acc.x += cm[t][0] * r.x;
      acc.y += cm[t][1] * r.y;
      acc.z += cm[t][2] * r.z;
      acc.w += cm[t][3] * r.w;
    }
    nat_f4 accn = {acc.x, acc.y, acc.z, acc.w};
    __builtin_nontemporal_store(accn, (nat_f4*)(out + outb + (size_t)(C_ + c) * HW_ + p0));
  }
  if (ctile == 0) {
    nat_f4 cmv = {cmask[0], cmask[1], cmask[2], cmask[3]};
    __builtin_nontemporal_store(cmv, (nat_f4*)(out + outb + (size_t)256 * HW_ + p0));
    __builtin_nontemporal_store(cmv, (nat_f4*)(out_cmask + (size_t)b * HW_ + p0));
  }
}

extern "C" void kernel_launch(void* const* d_in, const int* in_sizes, int n_in,
                              void* d_out, int out_size, void* d_ws, size_t ws_size,
                              hipStream_t stream) {
  const float* values = (const float*)d_in[0];   // (9,4,128,96,96)
  const float* tvmap  = (const float*)d_in[1];   // (4,1,384,384)
  const float* rvmaps = (const float*)d_in[2];   // (8,4,1,384,384)
  float* out = (float*)d_out;

  // workspace layout (floats) -- ~1.4 MB
  float* ws      = (float*)d_ws;
  float* rv      = ws;                                   // T*B*HW = 294912
  float* tv      = rv + (size_t)T_ * B_ * HW_;           // B*HW   = 36864
  float* gs_part = tv + (size_t)B_ * HW_;                // T*B*C*3 = 12288

  // output layout: out(4,257,96,96) | c_mask(4,1,96,96) | gs(8,4)
  float* out_cmask = out + (size_t)B_ * 257 * HW_;
  float* out_gs    = out_cmask + (size_t)B_ * HW_;

  hipLaunchKernelGGL(k_resize, dim3(6, 36),      dim3(384), 0, stream, rvmaps, tvmap, rv, tv);
  hipLaunchKernelGGL(k_gs,     dim3(3, C_, B_),  dim3(256), 0, stream, values, rv, tv, gs_part, out);
  hipLaunchKernelGGL(k_epi,    dim3(16, 9, B_),  dim3(256), 0, stream, values, rv, tv, gs_part, out, out_cmask, out_gs);
}

// Round 7
// 321.746 us; speedup vs baseline: 1.0326x; 1.0326x over previous
//
#include <hip/hip_runtime.h>
#include <math.h>

#define T_ 8
#define B_ 4
#define C_ 128
#define HW_ 9216        // 96*96
#define IN_HW_ 147456   // 384*384

typedef float nat_f4 __attribute__((ext_vector_type(4)));  // nontemporal stores

// f64 filter weights (8-tap triangle, edge-renormalized)
__device__ static const double d_wm[8]  = {0.03125, 0.09375, 0.15625, 0.21875,
                                           0.21875, 0.15625, 0.09375, 0.03125};
__device__ static const double d_w0[8]  = {0.0, 0.0, 0.625/3.5, 0.875/3.5,
                                           0.875/3.5, 0.625/3.5, 0.375/3.5, 0.125/3.5};
__device__ static const double d_w95[8] = {0.125/3.5, 0.375/3.5, 0.625/3.5, 0.875/3.5,
                                           0.875/3.5, 0.625/3.5, 0.0, 0.0};

// shuffle+LDS block sum (256 threads). Trailing sync: safe to call repeatedly.
__device__ __forceinline__ float block_sum_256(float v) {
  v += __shfl_xor(v, 1);
  v += __shfl_xor(v, 2);
  v += __shfl_xor(v, 4);
  v += __shfl_xor(v, 8);
  v += __shfl_xor(v, 16);
  v += __shfl_xor(v, 32);
  __shared__ float s[4];
  int lane = threadIdx.x & 63, wv = threadIdx.x >> 6;
  if (lane == 0) s[wv] = v;
  __syncthreads();
  float r = s[0] + s[1] + s[2] + s[3];
  __syncthreads();
  return r;
}

// ---------------------------------------------------------------------------
// k_resize: 384->96 antialias resize + binarize for all 36 mask images.
// (verified in rounds 5/6 -- unchanged)
// ---------------------------------------------------------------------------
__global__ __launch_bounds__(384) void k_resize(const float* __restrict__ rvmaps,
                                                const float* __restrict__ tvmap,
                                                float* __restrict__ rv,
                                                float* __restrict__ tv) {
  const int job = blockIdx.y;
  const float* img = (job < 32) ? rvmaps + (size_t)job * IN_HW_
                                : tvmap  + (size_t)(job - 32) * IN_HW_;
  float* dst = (job < 32) ? rv + (size_t)job * HW_
                          : tv + (size_t)(job - 32) * HW_;
  const int x  = threadIdx.x % 96;
  const int yg = threadIdx.x / 96;           // 0..3
  const int y0 = blockIdx.x * 16 + yg * 4;   // 4 output rows per thread

  const double* wys[4];
#pragma unroll
  for (int i = 0; i < 4; ++i) {
    int y = y0 + i;
    wys[i] = (y == 0) ? d_w0 : (y == 95 ? d_w95 : d_wm);
  }

  double acc0 = 0.0, acc1 = 0.0, acc2 = 0.0, acc3 = 0.0;
  const int base = 4 * y0 - 2;                       // ky = jy - base - 4*i
  const int jy_lo = base < 0 ? 0 : base;
  const int jy_hi_raw = 4 * (y0 + 3) + 5;
  const int jy_hi = jy_hi_raw > 383 ? 383 : jy_hi_raw;

  for (int jy = jy_lo; jy <= jy_hi; ++jy) {
    const float* row = img + (size_t)jy * 384;
    double ra;
    if (x == 0) {
      const float4 q0 = *(const float4*)(row);       // jx 0..3
      const float4 q1 = *(const float4*)(row + 4);   // jx 4..7
      ra = d_w0[2] * (double)q0.x + d_w0[3] * (double)q0.y +
           d_w0[4] * (double)q0.z + d_w0[5] * (double)q0.w +
           d_w0[6] * (double)q1.x + d_w0[7] * (double)q1.y;
    } else if (x == 95) {
      const float4 q0 = *(const float4*)(row + 376); // jx 376..379
      const float4 q1 = *(const float4*)(row + 380); // jx 380..383
      ra = d_w95[0] * (double)q0.z + d_w95[1] * (double)q0.w +
           d_w95[2] * (double)q1.x + d_w95[3] * (double)q1.y +
           d_w95[4] * (double)q1.z + d_w95[5] * (double)q1.w;
    } else {
      const int b0 = 4 * x - 4;                      // multiple of 4 -> 16B aligned
      const float4 q0 = *(const float4*)(row + b0);
      const float4 q1 = *(const float4*)(row + b0 + 4);
      const float4 q2 = *(const float4*)(row + b0 + 8);
      ra = d_wm[0] * (double)q0.z + d_wm[1] * (double)q0.w +
           d_wm[2] * (double)q1.x + d_wm[3] * (double)q1.y +
           d_wm[4] * (double)q1.z + d_wm[5] * (double)q1.w +
           d_wm[6] * (double)q2.x + d_wm[7] * (double)q2.y;
    }
    {
      int ky = jy - base;
      if (ky >= 0 && ky < 8) acc0 += wys[0][ky] * ra;
      ky -= 4;
      if (ky >= 0 && ky < 8) acc1 += wys[1][ky] * ra;
      ky -= 4;
      if (ky >= 0 && ky < 8) acc2 += wys[2][ky] * ra;
      ky -= 4;
      if (ky >= 0 && ky < 8) acc3 += wys[3][ky] * ra;
    }
  }
  dst[(size_t)(y0 + 0) * 96 + x] = (acc0 > 0.5) ? 1.0f : 0.0f;
  dst[(size_t)(y0 + 1) * 96 + x] = (acc1 > 0.5) ? 1.0f : 0.0f;
  dst[(size_t)(y0 + 2) * 96 + x] = (acc2 > 0.5) ? 1.0f : 0.0f;
  dst[(size_t)(y0 + 3) * 96 + x] = (acc3 > 0.5) ? 1.0f : 0.0f;
}

// ---------------------------------------------------------------------------
// k_gs: t-major gs partials + t_feat passthrough. block = (ptile, c, b).
// ALL 18 global float4 loads batched into registers BEFORE any FMA
// (launch_bounds(256,2) lifts the VGPR cap so the compiler keeps them in
// flight -- round-4 profile showed VGPR=60 load-serialized code at 475 GB/s).
// grid: (9, C_, B_) x 256.
// ---------------------------------------------------------------------------
__global__ __launch_bounds__(256, 2) void k_gs(const float* __restrict__ values,
                                               const float* __restrict__ rv,
                                               const float* __restrict__ tv,
                                               float* __restrict__ gs_part,
                                               float* __restrict__ out) {
  const int ptile = blockIdx.x;       // 0..8
  const int c     = blockIdx.y;       // 0..127
  const int b     = blockIdx.z;       // 0..3
  const int tid   = threadIdx.x;
  const int p0 = ptile * 1024 + tid * 4;

  // batch-issue all loads (18 independent float4) for maximum MLP
  const float4 a   = *(const float4*)(values + ((size_t)b * C_ + c) * HW_ + p0);
  const float4 tvv = *(const float4*)(tv + (size_t)b * HW_ + p0);
  float4 rvv[T_], rr[T_];
#pragma unroll
  for (int t = 0; t < T_; ++t)
    rvv[t] = *(const float4*)(rv + ((size_t)(t * B_ + b)) * HW_ + p0);
#pragma unroll
  for (int t = 0; t < T_; ++t)
    rr[t] = *(const float4*)(values + ((size_t)((1 + t) * B_ + b) * C_ + c) * HW_ + p0);

  // t_feat passthrough (out channels 0..127)
  {
    nat_f4 an = {a.x, a.y, a.z, a.w};
    __builtin_nontemporal_store(an,
        (nat_f4*)(out + (size_t)b * 257 * HW_ + (size_t)c * HW_ + p0));
  }

  // ma = (tv*a): exact (tv is 0/1); then rv*(ma)*r: exact (rv is 0/1).
  const float max_ = tvv.x * a.x, may_ = tvv.y * a.y;
  const float maz_ = tvv.z * a.z, maw_ = tvv.w * a.w;
  float acc[T_];
#pragma unroll
  for (int t = 0; t < T_; ++t) {
    acc[t] = (rvv[t].x * max_) * rr[t].x + (rvv[t].y * may_) * rr[t].y +
             (rvv[t].z * maz_) * rr[t].z + (rvv[t].w * maw_) * rr[t].w;
  }

  __shared__ float sred[4][T_];
  const int lane = tid & 63, wv = tid >> 6;
#pragma unroll
  for (int t = 0; t < T_; ++t) {
    float v = acc[t];
    v += __shfl_xor(v, 1);
    v += __shfl_xor(v, 2);
    v += __shfl_xor(v, 4);
    v += __shfl_xor(v, 8);
    v += __shfl_xor(v, 16);
    v += __shfl_xor(v, 32);
    if (lane == 0) sred[wv][t] = v;
  }
  __syncthreads();
  if (tid < T_) {
    const int t = tid;
    const float s = sred[0][t] + sred[1][t] + sred[2][t] + sred[3][t];
    gs_part[(size_t)(t * B_ + b) * (C_ * 9) + c * 9 + ptile] = s;
  }
}

// ---------------------------------------------------------------------------
// k_fin: per-tb v_sum (exact 0/1 sum of rv*tv) + gs_part reduce + finalize.
// grid: 32 blocks x 256.  (round-5 verified version)
// ---------------------------------------------------------------------------
__global__ __launch_bounds__(256) void k_fin(const float* __restrict__ rv,
                                             const float* __restrict__ tv,
                                             const float* __restrict__ gs_part,
                                             float* __restrict__ gsar,
                                             float* __restrict__ out_gs) {
  const int tb = blockIdx.x;          // 0..31
  const int b  = tb % B_;
  const int tid = threadIdx.x;

  const float4* pr = (const float4*)(rv + (size_t)tb * HW_);
  const float4* pt = (const float4*)(tv + (size_t)b  * HW_);
  float vs = 0.f;
  for (int i = tid; i < HW_ / 4; i += 256) {     // 9 iters
    const float4 r = pr[i], t = pt[i];
    vs += r.x * t.x + r.y * t.y + r.z * t.z + r.w * t.w;
  }
  vs = block_sum_256(vs);                        // exact: sum of 0/1 floats

  const float4* pg = (const float4*)(gs_part + (size_t)tb * (C_ * 9));
  float s = 0.f;
  for (int i = tid; i < (C_ * 9) / 4; i += 256) {  // 288 float4
    const float4 v = pg[i];
    s += v.x + v.y + v.z + v.w;
  }
  s = block_sum_256(s);

  if (tid == 0) {
    const bool empty = vs < 1e-4f;
    const float g = (empty ? 0.f : s) / (vs + (empty ? 1.f : 0.f)) / (float)C_;
    gsar[tb] = g;
    out_gs[tb] = g;
  }
}

// ---------------------------------------------------------------------------
// k_epi: per-pixel softmax over t + c_out + cmask. Round-5 grid (32,9,B_),
// 4 ch/block; r_feats loads batched per cc; __expf; launch_bounds(256,2).
// ---------------------------------------------------------------------------
__global__ __launch_bounds__(256, 2) void k_epi(const float* __restrict__ values,
                                                const float* __restrict__ rv,
                                                const float* __restrict__ gs,
                                                float* __restrict__ out,
                                                float* __restrict__ out_cmask) {
  const int ctile = blockIdx.x;       // 0..31
  const int ptile = blockIdx.y;       // 0..8
  const int b     = blockIdx.z;       // 0..3
  const int tid   = threadIdx.x;
  __shared__ float gsh[T_];
  if (tid < T_) gsh[tid] = gs[tid * B_ + b];
  __syncthreads();

  const int p0 = ptile * 1024 + tid * 4;

  float4 rv4[T_];
#pragma unroll
  for (int t = 0; t < T_; ++t)
    rv4[t] = *(const float4*)(rv + ((size_t)(t * B_ + b)) * HW_ + p0);

  float cm[T_][4];
  float cmask[4];
#pragma unroll
  for (int j = 0; j < 4; ++j) {
    float mv[T_];
    float mx = -1e30f;
#pragma unroll
    for (int t = 0; t < T_; ++t) {
      const float rvv = ((const float*)&rv4[t])[j];
      mv[t] = gsh[t] * rvv;
      mx = fmaxf(mx, mv[t]);
    }
    float e[T_];
    float ms = 0.f;
#pragma unroll
    for (int t = 0; t < T_; ++t) {
      const float rvv = ((const float*)&rv4[t])[j];
      e[t] = __expf(mv[t] - mx) * rvv;
      ms += e[t];
    }
    if (ms < 1e-4f) ms += 1.f;
    const float inv = 1.f / ms;
    float cs = 0.f;
#pragma unroll
    for (int t = 0; t < T_; ++t) {
      cm[t][j] = e[t] * inv;
      cs += cm[t][j] * ((const float*)&rv4[t])[j];
    }
    cmask[j] = 1.f - cs;
  }

  const size_t outb = (size_t)b * 257 * HW_;
#pragma unroll 1
  for (int cc = 0; cc < 4; ++cc) {
    const int c = ctile * 4 + cc;
    // batch the 8 independent r_feat loads before the FMA chain
    float4 rr[T_];
#pragma unroll
    for (int t = 0; t < T_; ++t)
      rr[t] = *(const float4*)(values + ((size_t)((1 + t) * B_ + b) * C_ + c) * HW_ + p0);
    float4 acc = {0.f, 0.f, 0.f, 0.f};
#pragma unroll
    for (int t = 0; t < T_; ++t) {
      acc.x += cm[t][0] * rr[t].x;
      acc.y += cm[t][1] * rr[t].y;
      acc.z += cm[t][2] * rr[t].z;
      acc.w += cm[t][3] * rr[t].w;
    }
    nat_f4 accn = {acc.x, acc.y, acc.z, acc.w};
    __builtin_nontemporal_store(accn, (nat_f4*)(out + outb + (size_t)(C_ + c) * HW_ + p0));
  }
  if (ctile == 0) {
    nat_f4 cmv = {cmask[0], cmask[1], cmask[2], cmask[3]};
    __builtin_nontemporal_store(cmv, (nat_f4*)(out + outb + (size_t)256 * HW_ + p0));
    __builtin_nontemporal_store(cmv, (nat_f4*)(out_cmask + (size_t)b * HW_ + p0));
  }
}

extern "C" void kernel_launch(void* const* d_in, const int* in_sizes, int n_in,
                              void* d_out, int out_size, void* d_ws, size_t ws_size,
                              hipStream_t stream) {
  const float* values = (const float*)d_in[0];   // (9,4,128,96,96)
  const float* tvmap  = (const float*)d_in[1];   // (4,1,384,384)
  const float* rvmaps = (const float*)d_in[2];   // (8,4,1,384,384)
  float* out = (float*)d_out;

  // workspace layout (floats) -- ~1.5 MB
  float* ws      = (float*)d_ws;
  float* rv      = ws;                                   // T*B*HW = 294912
  float* tv      = rv + (size_t)T_ * B_ * HW_;           // B*HW   = 36864
  float* gs_part = tv + (size_t)B_ * HW_;                // T*B*C*9 = 36864
  float* gsar    = gs_part + (size_t)T_ * B_ * C_ * 9;   // 32

  // output layout: out(4,257,96,96) | c_mask(4,1,96,96) | gs(8,4)
  float* out_cmask = out + (size_t)B_ * 257 * HW_;
  float* out_gs    = out_cmask + (size_t)B_ * HW_;

  hipLaunchKernelGGL(k_resize, dim3(6, 36),      dim3(384), 0, stream, rvmaps, tvmap, rv, tv);
  hipLaunchKernelGGL(k_gs,     dim3(9, C_, B_),  dim3(256), 0, stream, values, rv, tv, gs_part, out);
  hipLaunchKernelGGL(k_fin,    dim3(32),         dim3(256), 0, stream, rv, tv, gs_part, gsar, out_gs);
  hipLaunchKernelGGL(k_epi,    dim3(32, 9, B_),  dim3(256), 0, stream, values, rv, gsar, out, out_cmask);
}